// Round 8
// baseline (465.111 us; speedup 1.0000x reference)
//
#include <hip/hip_runtime.h>
#include <math.h>

#define LQ_ 5440
#define NB_ 8
#define NQ_ (NB_ * LQ_)   // 43520
#define D_  256
#define NH_ 8
#define HD_ 32

typedef __attribute__((ext_vector_type(8))) short short8;
typedef __attribute__((ext_vector_type(4))) float f32x4;

__device__ __forceinline__ ushort f2bf(float f) {
    union { float f; unsigned u; } v; v.f = f;
    unsigned u = v.u;
    unsigned r = (u + 0x7FFFu + ((u >> 16) & 1u)) >> 16;
    return (ushort)r;
}
__device__ __forceinline__ float bf2f(ushort u) {
    union { unsigned u; float f; } v; v.u = ((unsigned)u) << 16; return v.f;
}

// async global->LDS, 16 B per lane. LDS dest = wave-uniform base + lane*16.
__device__ __forceinline__ void gload_lds16(const void* g, void* l) {
    __builtin_amdgcn_global_load_lds(
        (const __attribute__((address_space(1))) void*)g,
        (__attribute__((address_space(3))) void*)l, 16, 0, 0);
}

// raw workgroup barrier, fenced so no memory op is scheduled across it.
__device__ __forceinline__ void wg_barrier() {
    __builtin_amdgcn_sched_barrier(0);
    __builtin_amdgcn_s_barrier();
    __builtin_amdgcn_sched_barrier(0);
}

// bijective XCD-chunk swizzle.
__device__ __forceinline__ int xcd_swz(int flat, int nwg) {
    const int xc  = flat & 7;
    const int sl  = flat >> 3;
    const int q8  = nwg >> 3;
    const int rm8 = nwg & 7;
    return (xc < rm8 ? xc * (q8 + 1) : rm8 * (q8 + 1) + (xc - rm8) * q8) + sl;
}

// ---------------------------------------------------------------------------
// Fused prep: ONE launch for bf16 input casts + all 6 weight transposes.
// ---------------------------------------------------------------------------
#define TPREP_ 736

__global__ __launch_bounds__(256)
void prep(const float* __restrict__ src, const float* __restrict__ pos,
          ushort* __restrict__ s_bf, ushort* __restrict__ q_bf,
          const float* __restrict__ Wv, const float* __restrict__ Woff,
          const float* __restrict__ Wattn, const float* __restrict__ Wout,
          const float* __restrict__ W1, const float* __restrict__ W2,
          ushort* __restrict__ Wv_t, ushort* __restrict__ Woff_t,
          ushort* __restrict__ Wattn_t, ushort* __restrict__ Wout_t,
          ushort* __restrict__ W1_t, ushort* __restrict__ W2_t) {
    __shared__ float tile[32][33];
    const int bid = blockIdx.x;
    const int tid = threadIdx.x;

    if (bid >= TPREP_) {
        const int i = (bid - TPREP_) * 256 + tid;
        const float4 s = ((const float4*)src)[i];
        const float4 p = ((const float4*)pos)[i];
        ushort4 a, b;
        a.x = f2bf(s.x); a.y = f2bf(s.y); a.z = f2bf(s.z); a.w = f2bf(s.w);
        b.x = f2bf(s.x + p.x); b.y = f2bf(s.y + p.y);
        b.z = f2bf(s.z + p.z); b.w = f2bf(s.w + p.w);
        ((ushort4*)s_bf)[i] = a;
        ((ushort4*)q_bf)[i] = b;
        return;
    }

    const float* W; ushort* Wt; int K, N, bx, by;
    if (bid < 64)       { W = Wv;    Wt = Wv_t;    K = 256;  N = 256;  bx = bid % 8;         by = bid / 8; }
    else if (bid < 128) { W = Woff;  Wt = Woff_t;  K = 256;  N = 256;  bx = (bid-64) % 8;    by = (bid-64) / 8; }
    else if (bid < 160) { W = Wattn; Wt = Wattn_t; K = 256;  N = 128;  bx = (bid-128) % 4;   by = (bid-128) / 4; }
    else if (bid < 224) { W = Wout;  Wt = Wout_t;  K = 256;  N = 256;  bx = (bid-160) % 8;   by = (bid-160) / 8; }
    else if (bid < 480) { W = W1;    Wt = W1_t;    K = 256;  N = 1024; bx = (bid-224) % 32;  by = (bid-224) / 32; }
    else                { W = W2;    Wt = W2_t;    K = 1024; N = 256;  bx = (bid-480) % 8;   by = (bid-480) / 8; }

    const int tx = tid & 31;
    const int ty = tid >> 5;
    for (int i = ty; i < 32; i += 8)
        tile[i][tx] = W[(size_t)(by * 32 + i) * N + bx * 32 + tx];
    __syncthreads();
    for (int i = ty; i < 32; i += 8)
        Wt[(size_t)(bx * 32 + i) * K + by * 32 + tx] = f2bf(tile[tx][i]);
}

// ---------------------------------------------------------------------------
// Shared MFMA GEMM body (128x128 tile, BK=64, 4 waves, 4x4 16x16x32/wave).
// Double-buffered, counted vmcnt.
// ---------------------------------------------------------------------------
#define BM 128
#define BN 128
#define BK 64

__device__ __forceinline__ void gemm_body(
    ushort* __restrict__ lAb, ushort* __restrict__ lBb,
    const ushort* __restrict__ A, const ushort* __restrict__ Bt,
    const float* __restrict__ bias, float* __restrict__ Cf,
    ushort* __restrict__ Cb, int N, int K, int relu, int col0, int row0) {
    const int t    = threadIdx.x;
    const int w    = t >> 6;
    const int lr   = t & 15;
    const int quad = (t >> 4) & 3;
    const int wm   = (w >> 1) * 64;
    const int wn   = (w & 1) * 64;

    f32x4 acc[4][4];
    #pragma unroll
    for (int i = 0; i < 4; ++i)
        #pragma unroll
        for (int j = 0; j < 4; ++j)
            acc[i][j] = (f32x4){0.f, 0.f, 0.f, 0.f};

    const int sr = t >> 3;
    const int sc = (t & 7) * 8;
    const size_t aoff = (size_t)(row0 + sr) * K + sc;
    const size_t boff = (size_t)(col0 + sr) * K + sc;
    const int wb = w * 1024;

    auto stage = [&](int buf, int k0) {
        char* la = (char*)(lAb + buf * (BM * BK)) + wb;
        char* lb = (char*)(lBb + buf * (BN * BK)) + wb;
        #pragma unroll
        for (int g = 0; g < 4; ++g) {
            gload_lds16(A  + aoff + k0 + (size_t)g * 32 * K, la + g * 4096);
            gload_lds16(Bt + boff + k0 + (size_t)g * 32 * K, lb + g * 4096);
        }
    };

    stage(0, 0);
    int cur = 0;
    for (int k0 = 0; k0 < K; k0 += BK) {
        if (k0 + BK < K) {
            stage(cur ^ 1, k0 + BK);
            asm volatile("s_waitcnt vmcnt(8)" ::: "memory");
        } else {
            asm volatile("s_waitcnt vmcnt(0)" ::: "memory");
        }
        wg_barrier();
        const ushort* pA = lAb + cur * (BM * BK);
        const ushort* pB = lBb + cur * (BN * BK);
        #pragma unroll
        for (int kk = 0; kk < 2; ++kk) {
            short8 af[4], bfr[4];
            #pragma unroll
            for (int i = 0; i < 4; ++i)
                af[i] = *(const short8*)(pA + (wm + i * 16 + lr) * BK + kk * 32 + quad * 8);
            #pragma unroll
            for (int j = 0; j < 4; ++j)
                bfr[j] = *(const short8*)(pB + (wn + j * 16 + lr) * BK + kk * 32 + quad * 8);
            #pragma unroll
            for (int i = 0; i < 4; ++i)
                #pragma unroll
                for (int j = 0; j < 4; ++j)
                    acc[i][j] = __builtin_amdgcn_mfma_f32_16x16x32_bf16(af[i], bfr[j], acc[i][j], 0, 0, 0);
        }
        wg_barrier();
        cur ^= 1;
    }

    #pragma unroll
    for (int j = 0; j < 4; ++j) {
        const int col = col0 + wn + j * 16 + lr;
        const float bb = bias ? bias[col] : 0.f;
        #pragma unroll
        for (int i = 0; i < 4; ++i) {
            const int rbase = row0 + wm + i * 16 + quad * 4;
            #pragma unroll
            for (int r = 0; r < 4; ++r) {
                float v = acc[i][j][r] + bb;
                if (relu) v = fmaxf(v, 0.f);
                if (Cf) Cf[(size_t)(rbase + r) * N + col] = v;
                else    Cb[(size_t)(rbase + r) * N + col] = f2bf(v);
            }
        }
    }
}

// generic GEMM (used for FFN1): grid (N/BN, M/BM), XCD-chunked.
__global__ __launch_bounds__(256)
void mfma_gemm(const ushort* __restrict__ A, const ushort* __restrict__ Bt,
               const float* __restrict__ bias, float* __restrict__ Cf,
               ushort* __restrict__ Cb, int N, int K, int relu) {
    __shared__ ushort lA[2][BM * BK];
    __shared__ ushort lB[2][BN * BK];
    const int nt  = gridDim.x;
    const int wi  = xcd_swz(blockIdx.y * nt + blockIdx.x, nt * gridDim.y);
    gemm_body(&lA[0][0], &lB[0][0], A, Bt, bias, Cf, Cb, N, K, relu,
              (wi % nt) * BN, (wi / nt) * BM);
}

// fused value+comb GEMM: grid 1700 = 340 row panels x (2 value + 3 comb cols).
__global__ __launch_bounds__(256)
void gemm_vc(const ushort* __restrict__ s_bf, const ushort* __restrict__ q_bf,
             const ushort* __restrict__ Wv_t, const ushort* __restrict__ Woff_t,
             const float* __restrict__ b_value,
             ushort* __restrict__ val_bf, ushort* __restrict__ comb_bf) {
    __shared__ ushort lA[2][BM * BK];
    __shared__ ushort lB[2][BN * BK];
    const int wi   = xcd_swz(blockIdx.x, gridDim.x);
    const int ci   = wi % 5;
    const int row0 = (wi / 5) * BM;
    if (ci < 2)
        gemm_body(&lA[0][0], &lB[0][0], s_bf, Wv_t, b_value, nullptr, val_bf,
                  256, 256, 0, ci * BN, row0);
    else
        gemm_body(&lA[0][0], &lB[0][0], q_bf, Woff_t, nullptr, nullptr, comb_bf,
                  384, 256, 0, (ci - 2) * BN, row0);
}

// ---------------------------------------------------------------------------
// GEMM + residual + LayerNorm fused, v2 (occupancy-correct geometry).
// GM=64 rows/block, GN=256 (= full N), GBK=32:
//   LDS = 2 x (64x32 + 256x32) x 2B = 40 KiB -> 4 blocks/CU (v1: 80K -> 1).
//   y = LN(res + A@Bt^T + bias) * g + be ; fp32 outf and/or bf16 outb.
// Staging 5 loads/tile (A:1, B:4), counted vmcnt(5). 16 MFMA/iter.
// Row stats: 16-lane shfl + cross-wave LDS reduce overlaid on dead A tile.
// ---------------------------------------------------------------------------
#define GM 64
#define GN 256
#define GBK 32

__global__ __launch_bounds__(256)
void gemm_ln(const ushort* __restrict__ A, const ushort* __restrict__ Bt,
             const float* __restrict__ bias, const float* __restrict__ res,
             float* __restrict__ outf, ushort* __restrict__ outb,
             const float* __restrict__ g, const float* __restrict__ be, int K) {
    __shared__ ushort lA[2][GM * GBK];   // 2 x 4 KiB
    __shared__ ushort lB[2][GN * GBK];   // 2 x 16 KiB
    const int t    = threadIdx.x;
    const int wi   = xcd_swz(blockIdx.x, gridDim.x);
    const int row0 = wi * GM;
    const int w    = t >> 6;
    const int lr   = t & 15;
    const int quad = (t >> 4) & 3;
    const int wn   = w * 64;

    f32x4 acc[4][4];
    #pragma unroll
    for (int i = 0; i < 4; ++i)
        #pragma unroll
        for (int j = 0; j < 4; ++j)
            acc[i][j] = (f32x4){0.f, 0.f, 0.f, 0.f};

    // staging: lane t covers row t>>2 (0..63), k-elems (t&3)*8..+7.
    // LDS byte t*16 (+ g*4096 for B row-groups) == wave base w*1024 + lane*16.
    const int arow = t >> 2;
    const int ak   = (t & 3) * 8;
    const size_t aoff = (size_t)(row0 + arow) * K + ak;
    const int wb = w * 1024;

    auto stage = [&](int buf, int k0) {
        char* la = (char*)(lA[buf]) + wb;
        char* lb = (char*)(lB[buf]) + wb;
        gload_lds16(A + aoff + k0, la);
        #pragma unroll
        for (int gb = 0; gb < 4; ++gb)
            gload_lds16(Bt + (size_t)(arow + gb * 64) * K + ak + k0, lb + gb * 4096);
    };

    stage(0, 0);                       // 5 loads in flight
    int cur = 0;
    for (int k0 = 0; k0 < K; k0 += GBK) {
        if (k0 + GBK < K) {
            stage(cur ^ 1, k0 + GBK);  // 10 in flight
            asm volatile("s_waitcnt vmcnt(5)" ::: "memory");   // prev tile landed
        } else {
            asm volatile("s_waitcnt vmcnt(0)" ::: "memory");
        }
        wg_barrier();
        const ushort* pA = lA[cur];
        const ushort* pB = lB[cur];
        short8 af[4], bfr[4];
        #pragma unroll
        for (int i = 0; i < 4; ++i)
            af[i] = *(const short8*)(pA + (i * 16 + lr) * GBK + quad * 8);
        #pragma unroll
        for (int j = 0; j < 4; ++j)
            bfr[j] = *(const short8*)(pB + (wn + j * 16 + lr) * GBK + quad * 8);
        #pragma unroll
        for (int i = 0; i < 4; ++i)
            #pragma unroll
            for (int j = 0; j < 4; ++j)
                acc[i][j] = __builtin_amdgcn_mfma_f32_16x16x32_bf16(af[i], bfr[j], acc[i][j], 0, 0, 0);
        wg_barrier();
        cur ^= 1;
    }

    // ---- epilogue: bias + residual, then per-row LN ----
    #pragma unroll
    for (int j = 0; j < 4; ++j) {
        const int col = wn + j * 16 + lr;
        const float bb = bias[col];
        #pragma unroll
        for (int i = 0; i < 4; ++i) {
            const int rbase = row0 + i * 16 + quad * 4;
            #pragma unroll
            for (int r = 0; r < 4; ++r)
                acc[i][j][r] += bb + res[(size_t)(rbase + r) * 256 + col];
        }
    }

    float* reds = (float*)&lA[0][0];          // [4 waves][64 rows] sums (2 KiB)
    float* redq = reds + 256;                 // [4 waves][64 rows] sumsq
    float mu[4][4], rstd[4][4];
    #pragma unroll
    for (int i = 0; i < 4; ++i)
        #pragma unroll
        for (int r = 0; r < 4; ++r) {
            float s = acc[i][0][r] + acc[i][1][r] + acc[i][2][r] + acc[i][3][r];
            float q = acc[i][0][r]*acc[i][0][r] + acc[i][1][r]*acc[i][1][r]
                    + acc[i][2][r]*acc[i][2][r] + acc[i][3][r]*acc[i][3][r];
            #pragma unroll
            for (int o = 1; o < 16; o <<= 1) {
                s += __shfl_xor(s, o);
                q += __shfl_xor(q, o);
            }
            if (lr == 0) {
                const int rl = i * 16 + quad * 4 + r;
                reds[w * 64 + rl] = s;
                redq[w * 64 + rl] = q;
            }
        }
    __syncthreads();
    #pragma unroll
    for (int i = 0; i < 4; ++i)
        #pragma unroll
        for (int r = 0; r < 4; ++r) {
            const int rl = i * 16 + quad * 4 + r;
            const float s = reds[rl] + reds[64 + rl] + reds[128 + rl] + reds[192 + rl];
            const float q = redq[rl] + redq[64 + rl] + redq[128 + rl] + redq[192 + rl];
            const float m = s * (1.f / 256.f);
            mu[i][r]   = m;
            rstd[i][r] = rsqrtf(q * (1.f / 256.f) - m * m + 1e-5f);
        }

    #pragma unroll
    for (int j = 0; j < 4; ++j) {
        const int col = wn + j * 16 + lr;
        const float gc = g[col];
        const float bc = be[col];
        #pragma unroll
        for (int i = 0; i < 4; ++i) {
            const int rbase = row0 + i * 16 + quad * 4;
            #pragma unroll
            for (int r = 0; r < 4; ++r) {
                const float y = (acc[i][j][r] - mu[i][r]) * rstd[i][r] * gc + bc;
                if (outf) outf[(size_t)(rbase + r) * 256 + col] = y;
                if (outb) outb[(size_t)(rbase + r) * 256 + col] = f2bf(y);
            }
        }
    }
}

// ---------------------------------------------------------------------------
// Fused softmax + deformable bilinear sampling.  (proven r4/r6 structure.)
// ---------------------------------------------------------------------------
__global__ __launch_bounds__(256)
void msda_sample(const ushort* __restrict__ value, const ushort* __restrict__ comb,
                 const float* __restrict__ b_off, const float* __restrict__ b_attn,
                 const float* __restrict__ refp, ushort* __restrict__ out) {
    __shared__ int   s_addr[256][4];
    __shared__ float s_w[256][4];

    const int t   = threadIdx.x;
    const int tq  = t >> 7;
    const int u   = t & 127;
    const int bid = blockIdx.x;
    const int swz = (bid & 7) * (NQ_ / 2 / 8) + (bid >> 3);
    const int nq  = swz * 2 + tq;
    const int n   = nq / LQ_;

    // ---------------- phase 1: (h,p) ----------------
    {
        const int h = u >> 4;
        const int p = u & 15;
        const int l = p >> 2;

        const int starts[4] = {0, 4096, 5120, 5376};
        const int Wl = 64 >> l;

        float a = bf2f(comb[(size_t)nq * 384 + 256 + u]) + b_attn[u];
        float m = a;
        #pragma unroll
        for (int o = 8; o > 0; o >>= 1) m = fmaxf(m, __shfl_xor(m, o));
        float e = __expf(a - m);
        float s = e;
        #pragma unroll
        for (int o = 8; o > 0; o >>= 1) s += __shfl_xor(s, o);
        const float wgt = e / s;

        const float rx = refp[(size_t)nq * 8 + l * 2 + 0];
        const float ry = refp[(size_t)nq * 8 + l * 2 + 1];
        const uint  opk = *(const uint*)(comb + (size_t)nq * 384 + u * 2);
        const float ox = bf2f((ushort)(opk & 0xffffu)) + b_off[u * 2 + 0];
        const float oy = bf2f((ushort)(opk >> 16))     + b_off[u * 2 + 1];

        const float fw = (float)Wl;
        const float x  = (rx + ox / fw) * fw - 0.5f;
        const float y  = (ry + oy / fw) * fw - 0.5f;
        const float x0f = floorf(x), y0f = floorf(y);
        const int   x0 = (int)x0f, y0 = (int)y0f;
        const float wx1 = x - x0f, wy1 = y - y0f;
        const float wx0 = 1.f - wx1, wy0 = 1.f - wy1;

        const float xm0 = (x0 >= 0 && x0 < Wl) ? 1.f : 0.f;
        const float xm1 = (x0 + 1 >= 0 && x0 + 1 < Wl) ? 1.f : 0.f;
        const float ym0 = (y0 >= 0 && y0 < Wl) ? 1.f : 0.f;
        const float ym1 = (y0 + 1 >= 0 && y0 + 1 < Wl) ? 1.f : 0.f;

        const int x0c = min(max(x0, 0), Wl - 1);
        const int x1c = min(max(x0 + 1, 0), Wl - 1);
        const int y0c = min(max(y0, 0), Wl - 1);
        const int y1c = min(max(y0 + 1, 0), Wl - 1);

        const int base = (n * LQ_ + starts[l]) * 512 + h * 64;
        s_addr[t][0] = base + (y0c * Wl + x0c) * 512;
        s_addr[t][1] = base + (y0c * Wl + x1c) * 512;
        s_addr[t][2] = base + (y1c * Wl + x0c) * 512;
        s_addr[t][3] = base + (y1c * Wl + x1c) * 512;
        s_w[t][0] = wgt * wy0 * wx0 * ym0 * xm0;
        s_w[t][1] = wgt * wy0 * wx1 * ym0 * xm1;
        s_w[t][2] = wgt * wy1 * wx0 * ym1 * xm0;
        s_w[t][3] = wgt * wy1 * wx1 * ym1 * xm1;
    }
    __syncthreads();

    // ---------------- phase 2: (h,d2) ----------------
    {
        const int h   = u >> 4;
        const int d2  = u & 15;
        const int sb  = tq * 128 + h * 16;
        const uint dby = (uint)(d2 * 4);
        const char* vbase = (const char*)value;

        float acc0 = 0.f, acc1 = 0.f;
        #pragma unroll 8
        for (int p = 0; p < 16; ++p) {
            const int*   ap = s_addr[sb + p];
            const float* wp = s_w[sb + p];
            #pragma unroll
            for (int c = 0; c < 4; ++c) {
                const uint v = *(const uint*)(vbase + ((uint)ap[c] + dby));
                const float w = wp[c];
                union { uint u; float f; } lo, hi;
                lo.u = v << 16;
                hi.u = v & 0xffff0000u;
                acc0 = fmaf(lo.f, w, acc0);
                acc1 = fmaf(hi.f, w, acc1);
            }
        }
        const uint packed = (uint)f2bf(acc0) | ((uint)f2bf(acc1) << 16);
        ((uint*)out)[(size_t)nq * 128 + u] = packed;
    }
}

// ---------------------------------------------------------------------------
extern "C" void kernel_launch(void* const* d_in, const int* in_sizes, int n_in,
                              void* d_out, int out_size, void* d_ws, size_t ws_size,
                              hipStream_t stream) {
    const float* src     = (const float*)d_in[0];
    const float* pos     = (const float*)d_in[1];
    const float* refp    = (const float*)d_in[2];
    const float* W_value = (const float*)d_in[4];
    const float* b_value = (const float*)d_in[5];
    const float* W_off   = (const float*)d_in[6];
    const float* b_off   = (const float*)d_in[7];
    const float* W_attn  = (const float*)d_in[8];
    const float* b_attn  = (const float*)d_in[9];
    const float* W_out   = (const float*)d_in[10];
    const float* b_out   = (const float*)d_in[11];
    const float* ln1g    = (const float*)d_in[12];
    const float* ln1b    = (const float*)d_in[13];
    const float* W1      = (const float*)d_in[14];
    const float* b1      = (const float*)d_in[15];
    const float* W2      = (const float*)d_in[16];
    const float* b2      = (const float*)d_in[17];
    const float* ln2g    = (const float*)d_in[18];
    const float* ln2b    = (const float*)d_in[19];
    float* out = (float*)d_out;
    char*  ws  = (char*)d_ws;

    // ---- workspace layout (byte offsets) ----
    const size_t SZ_BF  = (size_t)NQ_ * 256 * 2;    // 22,282,240
    const size_t SZ_CB  = (size_t)NQ_ * 384 * 2;    // 33,423,360 (comb bf16)
    const size_t SZ_F   = (size_t)NQ_ * 256 * 4;    // 44,564,480
    ushort* s_bf    = (ushort*)(ws);                             // [0, 22.3M)
    ushort* q_bf    = (ushort*)(ws + SZ_BF);                     // [22.3M, 44.6M)
    ushort* val_bf  = (ushort*)(ws + 2 * SZ_BF);                 // [44.6M, 66.8M)
    ushort* comb    = (ushort*)(ws + 3 * SZ_BF);                 // [66.8M, 100.3M)
    ushort* samp_bf = (ushort*)(ws + 3 * SZ_BF + SZ_CB);         // [100.3M, 122.6M)
    ushort* h_bf    = (ushort*)(ws);                             // overlays [0, 89.1M): s/q/val/comb dead at FFN1
    char*   wbase   = ws + 3 * SZ_BF + SZ_CB + SZ_BF;            // 122.6M
    ushort* Wv_t    = (ushort*)(wbase);
    ushort* Woff_t  = (ushort*)(wbase + 131072);   // contiguous with Wattn_t -> one [384][256] Bt
    ushort* Wattn_t = (ushort*)(wbase + 262144);
    ushort* Wout_t  = (ushort*)(wbase + 327680);
    ushort* W1_t    = (ushort*)(wbase + 458752);
    ushort* W2_t    = (ushort*)(wbase + 983040);
    char*   fbase   = wbase + 1507328;                           // 124.1M
    float*  xf      = (float*)(fbase);                           // fp32 LN1 out
    ushort* x_bf    = (ushort*)(fbase + SZ_F);                   // bf16 LN1 out

    // 0. fused prep: bf16 inputs + all weight transposes (one launch)
    prep<<<dim3(TPREP_ + (NQ_ * 256 / 4) / 256), 256, 0, stream>>>(
        src, pos, s_bf, q_bf, W_value, W_off, W_attn, W_out, W1, W2,
        Wv_t, Woff_t, Wattn_t, Wout_t, W1_t, W2_t);

    const int MT = NQ_ / BM;  // 340

    // 1. fused: value = src @ Wv + bv (bf16), comb = q @ [Woff|Wattn] (bf16)
    gemm_vc<<<dim3(5 * MT), 256, 0, stream>>>(s_bf, q_bf, Wv_t, Woff_t, b_value, val_bf, comb);
    // 2. fused softmax + sampling -> bf16
    msda_sample<<<dim3(NQ_ / 2), 256, 0, stream>>>(val_bf, comb, b_off, b_attn, refp, samp_bf);
    // 3. x = LN(src + samp @ Wout + bout) -> fp32 xf + bf16 x_bf  (GEMM+LN fused)
    gemm_ln<<<dim3(NQ_ / GM), 256, 0, stream>>>(samp_bf, Wout_t, b_out, src,
                                                xf, x_bf, ln1g, ln1b, 256);
    // 4. h = relu(x @ W1 + b1) -> bf16
    mfma_gemm<<<dim3(8, MT), 256, 0, stream>>>(x_bf, W1_t, b1, nullptr, h_bf, 1024, 256, 1);
    // 5. out = LN(x + h @ W2 + b2)  (GEMM+LN fused, fp32 out)
    gemm_ln<<<dim3(NQ_ / GM), 256, 0, stream>>>(h_bf, W2_t, b2, xf,
                                                out, nullptr, ln2g, ln2b, 1024);
}

// Round 9
// 432.492 us; speedup vs baseline: 1.0754x; 1.0754x over previous
//
#include <hip/hip_runtime.h>
#include <math.h>

#define LQ_ 5440
#define NB_ 8
#define NQ_ (NB_ * LQ_)   // 43520
#define D_  256
#define NH_ 8
#define HD_ 32

typedef __attribute__((ext_vector_type(8))) short short8;
typedef __attribute__((ext_vector_type(4))) float f32x4;

__device__ __forceinline__ ushort f2bf(float f) {
    union { float f; unsigned u; } v; v.f = f;
    unsigned u = v.u;
    unsigned r = (u + 0x7FFFu + ((u >> 16) & 1u)) >> 16;
    return (ushort)r;
}
__device__ __forceinline__ float bf2f(ushort u) {
    union { unsigned u; float f; } v; v.u = ((unsigned)u) << 16; return v.f;
}

// async global->LDS, 16 B per lane. LDS dest = wave-uniform base + lane*16.
__device__ __forceinline__ void gload_lds16(const void* g, void* l) {
    __builtin_amdgcn_global_load_lds(
        (const __attribute__((address_space(1))) void*)g,
        (__attribute__((address_space(3))) void*)l, 16, 0, 0);
}

// raw workgroup barrier, fenced so no memory op is scheduled across it.
__device__ __forceinline__ void wg_barrier() {
    __builtin_amdgcn_sched_barrier(0);
    __builtin_amdgcn_s_barrier();
    __builtin_amdgcn_sched_barrier(0);
}

// bijective XCD-chunk swizzle.
__device__ __forceinline__ int xcd_swz(int flat, int nwg) {
    const int xc  = flat & 7;
    const int sl  = flat >> 3;
    const int q8  = nwg >> 3;
    const int rm8 = nwg & 7;
    return (xc < rm8 ? xc * (q8 + 1) : rm8 * (q8 + 1) + (xc - rm8) * q8) + sl;
}

// ---------------------------------------------------------------------------
// Fused prep: ONE launch for bf16 input casts + all 6 weight transposes.
// ---------------------------------------------------------------------------
#define TPREP_ 736

__global__ __launch_bounds__(256)
void prep(const float* __restrict__ src, const float* __restrict__ pos,
          ushort* __restrict__ s_bf, ushort* __restrict__ q_bf,
          const float* __restrict__ Wv, const float* __restrict__ Woff,
          const float* __restrict__ Wattn, const float* __restrict__ Wout,
          const float* __restrict__ W1, const float* __restrict__ W2,
          ushort* __restrict__ Wv_t, ushort* __restrict__ Woff_t,
          ushort* __restrict__ Wattn_t, ushort* __restrict__ Wout_t,
          ushort* __restrict__ W1_t, ushort* __restrict__ W2_t) {
    __shared__ float tile[32][33];
    const int bid = blockIdx.x;
    const int tid = threadIdx.x;

    if (bid >= TPREP_) {
        const int i = (bid - TPREP_) * 256 + tid;
        const float4 s = ((const float4*)src)[i];
        const float4 p = ((const float4*)pos)[i];
        ushort4 a, b;
        a.x = f2bf(s.x); a.y = f2bf(s.y); a.z = f2bf(s.z); a.w = f2bf(s.w);
        b.x = f2bf(s.x + p.x); b.y = f2bf(s.y + p.y);
        b.z = f2bf(s.z + p.z); b.w = f2bf(s.w + p.w);
        ((ushort4*)s_bf)[i] = a;
        ((ushort4*)q_bf)[i] = b;
        return;
    }

    const float* W; ushort* Wt; int K, N, bx, by;
    if (bid < 64)       { W = Wv;    Wt = Wv_t;    K = 256;  N = 256;  bx = bid % 8;         by = bid / 8; }
    else if (bid < 128) { W = Woff;  Wt = Woff_t;  K = 256;  N = 256;  bx = (bid-64) % 8;    by = (bid-64) / 8; }
    else if (bid < 160) { W = Wattn; Wt = Wattn_t; K = 256;  N = 128;  bx = (bid-128) % 4;   by = (bid-128) / 4; }
    else if (bid < 224) { W = Wout;  Wt = Wout_t;  K = 256;  N = 256;  bx = (bid-160) % 8;   by = (bid-160) / 8; }
    else if (bid < 480) { W = W1;    Wt = W1_t;    K = 256;  N = 1024; bx = (bid-224) % 32;  by = (bid-224) / 32; }
    else                { W = W2;    Wt = W2_t;    K = 1024; N = 256;  bx = (bid-480) % 8;   by = (bid-480) / 8; }

    const int tx = tid & 31;
    const int ty = tid >> 5;
    for (int i = ty; i < 32; i += 8)
        tile[i][tx] = W[(size_t)(by * 32 + i) * N + bx * 32 + tx];
    __syncthreads();
    for (int i = ty; i < 32; i += 8)
        Wt[(size_t)(bx * 32 + i) * K + by * 32 + tx] = f2bf(tile[tx][i]);
}

// ---------------------------------------------------------------------------
// Shared MFMA GEMM body (128x128 tile, BK=64, 4 waves, 4x4 16x16x32/wave).
// Double-buffered, counted vmcnt (waits only the PREVIOUS tile's 8 loads).
// ---------------------------------------------------------------------------
#define BM 128
#define BN 128
#define BK 64

__device__ __forceinline__ void gemm_body(
    ushort* __restrict__ lAb, ushort* __restrict__ lBb,
    const ushort* __restrict__ A, const ushort* __restrict__ Bt,
    const float* __restrict__ bias, float* __restrict__ Cf,
    ushort* __restrict__ Cb, int N, int K, int relu, int col0, int row0) {
    const int t    = threadIdx.x;
    const int w    = t >> 6;
    const int lr   = t & 15;
    const int quad = (t >> 4) & 3;
    const int wm   = (w >> 1) * 64;
    const int wn   = (w & 1) * 64;

    f32x4 acc[4][4];
    #pragma unroll
    for (int i = 0; i < 4; ++i)
        #pragma unroll
        for (int j = 0; j < 4; ++j)
            acc[i][j] = (f32x4){0.f, 0.f, 0.f, 0.f};

    const int sr = t >> 3;
    const int sc = (t & 7) * 8;
    const size_t aoff = (size_t)(row0 + sr) * K + sc;
    const size_t boff = (size_t)(col0 + sr) * K + sc;
    const int wb = w * 1024;

    auto stage = [&](int buf, int k0) {
        char* la = (char*)(lAb + buf * (BM * BK)) + wb;
        char* lb = (char*)(lBb + buf * (BN * BK)) + wb;
        #pragma unroll
        for (int g = 0; g < 4; ++g) {
            gload_lds16(A  + aoff + k0 + (size_t)g * 32 * K, la + g * 4096);
            gload_lds16(Bt + boff + k0 + (size_t)g * 32 * K, lb + g * 4096);
        }
    };

    stage(0, 0);
    int cur = 0;
    for (int k0 = 0; k0 < K; k0 += BK) {
        if (k0 + BK < K) {
            stage(cur ^ 1, k0 + BK);
            asm volatile("s_waitcnt vmcnt(8)" ::: "memory");
        } else {
            asm volatile("s_waitcnt vmcnt(0)" ::: "memory");
        }
        wg_barrier();
        const ushort* pA = lAb + cur * (BM * BK);
        const ushort* pB = lBb + cur * (BN * BK);
        #pragma unroll
        for (int kk = 0; kk < 2; ++kk) {
            short8 af[4], bfr[4];
            #pragma unroll
            for (int i = 0; i < 4; ++i)
                af[i] = *(const short8*)(pA + (wm + i * 16 + lr) * BK + kk * 32 + quad * 8);
            #pragma unroll
            for (int j = 0; j < 4; ++j)
                bfr[j] = *(const short8*)(pB + (wn + j * 16 + lr) * BK + kk * 32 + quad * 8);
            #pragma unroll
            for (int i = 0; i < 4; ++i)
                #pragma unroll
                for (int j = 0; j < 4; ++j)
                    acc[i][j] = __builtin_amdgcn_mfma_f32_16x16x32_bf16(af[i], bfr[j], acc[i][j], 0, 0, 0);
        }
        wg_barrier();
        cur ^= 1;
    }

    #pragma unroll
    for (int j = 0; j < 4; ++j) {
        const int col = col0 + wn + j * 16 + lr;
        const float bb = bias ? bias[col] : 0.f;
        #pragma unroll
        for (int i = 0; i < 4; ++i) {
            const int rbase = row0 + wm + i * 16 + quad * 4;
            #pragma unroll
            for (int r = 0; r < 4; ++r) {
                float v = acc[i][j][r] + bb;
                if (relu) v = fmaxf(v, 0.f);
                if (Cf) Cf[(size_t)(rbase + r) * N + col] = v;
                else    Cb[(size_t)(rbase + r) * N + col] = f2bf(v);
            }
        }
    }
}

// generic GEMM: grid (N/BN, M/BM), XCD-chunked bijective mapping.
__global__ __launch_bounds__(256)
void mfma_gemm(const ushort* __restrict__ A, const ushort* __restrict__ Bt,
               const float* __restrict__ bias, float* __restrict__ Cf,
               ushort* __restrict__ Cb, int N, int K, int relu) {
    __shared__ ushort lA[2][BM * BK];
    __shared__ ushort lB[2][BN * BK];
    const int nt  = gridDim.x;
    const int wi  = xcd_swz(blockIdx.y * nt + blockIdx.x, nt * gridDim.y);
    gemm_body(&lA[0][0], &lB[0][0], A, Bt, bias, Cf, Cb, N, K, relu,
              (wi % nt) * BN, (wi / nt) * BM);
}

// fused value+comb GEMM: grid 1700 = 340 row panels x (2 value + 3 comb cols).
__global__ __launch_bounds__(256)
void gemm_vc(const ushort* __restrict__ s_bf, const ushort* __restrict__ q_bf,
             const ushort* __restrict__ Wv_t, const ushort* __restrict__ Woff_t,
             const float* __restrict__ b_value,
             ushort* __restrict__ val_bf, ushort* __restrict__ comb_bf) {
    __shared__ ushort lA[2][BM * BK];
    __shared__ ushort lB[2][BN * BK];
    const int wi   = xcd_swz(blockIdx.x, gridDim.x);
    const int ci   = wi % 5;
    const int row0 = (wi / 5) * BM;
    if (ci < 2)
        gemm_body(&lA[0][0], &lB[0][0], s_bf, Wv_t, b_value, nullptr, val_bf,
                  256, 256, 0, ci * BN, row0);
    else
        gemm_body(&lA[0][0], &lB[0][0], q_bf, Woff_t, nullptr, nullptr, comb_bf,
                  384, 256, 0, (ci - 2) * BN, row0);
}

// ---------------------------------------------------------------------------
// Fused softmax + deformable bilinear sampling.  (proven r4/r6 structure:
// 2 queries/block, 128 threads/query, scalar FMA, XCD swizzle, bf16 comb.)
// ---------------------------------------------------------------------------
__global__ __launch_bounds__(256)
void msda_sample(const ushort* __restrict__ value, const ushort* __restrict__ comb,
                 const float* __restrict__ b_off, const float* __restrict__ b_attn,
                 const float* __restrict__ refp, ushort* __restrict__ out) {
    __shared__ int   s_addr[256][4];
    __shared__ float s_w[256][4];

    const int t   = threadIdx.x;
    const int tq  = t >> 7;
    const int u   = t & 127;
    const int bid = blockIdx.x;
    const int swz = (bid & 7) * (NQ_ / 2 / 8) + (bid >> 3);
    const int nq  = swz * 2 + tq;
    const int n   = nq / LQ_;

    // ---------------- phase 1: (h,p) ----------------
    {
        const int h = u >> 4;
        const int p = u & 15;
        const int l = p >> 2;

        const int starts[4] = {0, 4096, 5120, 5376};
        const int Wl = 64 >> l;

        float a = bf2f(comb[(size_t)nq * 384 + 256 + u]) + b_attn[u];
        float m = a;
        #pragma unroll
        for (int o = 8; o > 0; o >>= 1) m = fmaxf(m, __shfl_xor(m, o));
        float e = __expf(a - m);
        float s = e;
        #pragma unroll
        for (int o = 8; o > 0; o >>= 1) s += __shfl_xor(s, o);
        const float wgt = e / s;

        const float rx = refp[(size_t)nq * 8 + l * 2 + 0];
        const float ry = refp[(size_t)nq * 8 + l * 2 + 1];
        const uint  opk = *(const uint*)(comb + (size_t)nq * 384 + u * 2);
        const float ox = bf2f((ushort)(opk & 0xffffu)) + b_off[u * 2 + 0];
        const float oy = bf2f((ushort)(opk >> 16))     + b_off[u * 2 + 1];

        const float fw = (float)Wl;
        const float x  = (rx + ox / fw) * fw - 0.5f;
        const float y  = (ry + oy / fw) * fw - 0.5f;
        const float x0f = floorf(x), y0f = floorf(y);
        const int   x0 = (int)x0f, y0 = (int)y0f;
        const float wx1 = x - x0f, wy1 = y - y0f;
        const float wx0 = 1.f - wx1, wy0 = 1.f - wy1;

        const float xm0 = (x0 >= 0 && x0 < Wl) ? 1.f : 0.f;
        const float xm1 = (x0 + 1 >= 0 && x0 + 1 < Wl) ? 1.f : 0.f;
        const float ym0 = (y0 >= 0 && y0 < Wl) ? 1.f : 0.f;
        const float ym1 = (y0 + 1 >= 0 && y0 + 1 < Wl) ? 1.f : 0.f;

        const int x0c = min(max(x0, 0), Wl - 1);
        const int x1c = min(max(x0 + 1, 0), Wl - 1);
        const int y0c = min(max(y0, 0), Wl - 1);
        const int y1c = min(max(y0 + 1, 0), Wl - 1);

        const int base = (n * LQ_ + starts[l]) * 512 + h * 64;
        s_addr[t][0] = base + (y0c * Wl + x0c) * 512;
        s_addr[t][1] = base + (y0c * Wl + x1c) * 512;
        s_addr[t][2] = base + (y1c * Wl + x0c) * 512;
        s_addr[t][3] = base + (y1c * Wl + x1c) * 512;
        s_w[t][0] = wgt * wy0 * wx0 * ym0 * xm0;
        s_w[t][1] = wgt * wy0 * wx1 * ym0 * xm1;
        s_w[t][2] = wgt * wy1 * wx0 * ym1 * xm0;
        s_w[t][3] = wgt * wy1 * wx1 * ym1 * xm1;
    }
    __syncthreads();

    // ---------------- phase 2: (h,d2) ----------------
    {
        const int h   = u >> 4;
        const int d2  = u & 15;
        const int sb  = tq * 128 + h * 16;
        const uint dby = (uint)(d2 * 4);
        const char* vbase = (const char*)value;

        float acc0 = 0.f, acc1 = 0.f;
        #pragma unroll 8
        for (int p = 0; p < 16; ++p) {
            const int*   ap = s_addr[sb + p];
            const float* wp = s_w[sb + p];
            #pragma unroll
            for (int c = 0; c < 4; ++c) {
                const uint v = *(const uint*)(vbase + ((uint)ap[c] + dby));
                const float w = wp[c];
                union { uint u; float f; } lo, hi;
                lo.u = v << 16;
                hi.u = v & 0xffff0000u;
                acc0 = fmaf(lo.f, w, acc0);
                acc1 = fmaf(hi.f, w, acc1);
            }
        }
        const uint packed = (uint)f2bf(acc0) | ((uint)f2bf(acc1) << 16);
        ((uint*)out)[(size_t)nq * 128 + u] = packed;
    }
}

// ---------------------------------------------------------------------------
// x = LayerNorm(a + b); a fp32 residual, b bf16 GEMM output.
// Wave-per-row, float4/ushort4 per lane, shuffle-only reduce.
// grid = NQ/4, block = 256 (4 waves = 4 rows).
// ---------------------------------------------------------------------------
__global__ __launch_bounds__(256)
void add_ln(const float* __restrict__ a, const ushort* __restrict__ b,
            const float* __restrict__ g, const float* __restrict__ be,
            float* __restrict__ xf, ushort* __restrict__ xb) {
    const int row  = blockIdx.x * 4 + (threadIdx.x >> 6);
    const int lane = threadIdx.x & 63;
    const size_t base = (size_t)row * 256 + lane * 4;

    const float4  av = *(const float4*)(a + base);
    const ushort4 bv = *(const ushort4*)(b + base);
    float4 x;
    x.x = av.x + bf2f(bv.x); x.y = av.y + bf2f(bv.y);
    x.z = av.z + bf2f(bv.z); x.w = av.w + bf2f(bv.w);

    float s = x.x + x.y + x.z + x.w;
    #pragma unroll
    for (int o = 32; o > 0; o >>= 1) s += __shfl_xor(s, o);
    const float mu = s * (1.f / 256.f);

    float4 dx;
    dx.x = x.x - mu; dx.y = x.y - mu; dx.z = x.z - mu; dx.w = x.w - mu;
    float vv = dx.x * dx.x + dx.y * dx.y + dx.z * dx.z + dx.w * dx.w;
    #pragma unroll
    for (int o = 32; o > 0; o >>= 1) vv += __shfl_xor(vv, o);
    const float rstd = rsqrtf(vv * (1.f / 256.f) + 1e-5f);

    const float4 gv  = *(const float4*)(g  + lane * 4);
    const float4 bev = *(const float4*)(be + lane * 4);
    float4 y;
    y.x = dx.x * rstd * gv.x + bev.x;
    y.y = dx.y * rstd * gv.y + bev.y;
    y.z = dx.z * rstd * gv.z + bev.z;
    y.w = dx.w * rstd * gv.w + bev.w;

    *(float4*)(xf + base) = y;
    if (xb) {
        ushort4 yb;
        yb.x = f2bf(y.x); yb.y = f2bf(y.y); yb.z = f2bf(y.z); yb.w = f2bf(y.w);
        *(ushort4*)(xb + base) = yb;
    }
}

// ---------------------------------------------------------------------------
extern "C" void kernel_launch(void* const* d_in, const int* in_sizes, int n_in,
                              void* d_out, int out_size, void* d_ws, size_t ws_size,
                              hipStream_t stream) {
    const float* src     = (const float*)d_in[0];
    const float* pos     = (const float*)d_in[1];
    const float* refp    = (const float*)d_in[2];
    const float* W_value = (const float*)d_in[4];
    const float* b_value = (const float*)d_in[5];
    const float* W_off   = (const float*)d_in[6];
    const float* b_off   = (const float*)d_in[7];
    const float* W_attn  = (const float*)d_in[8];
    const float* b_attn  = (const float*)d_in[9];
    const float* W_out   = (const float*)d_in[10];
    const float* b_out   = (const float*)d_in[11];
    const float* ln1g    = (const float*)d_in[12];
    const float* ln1b    = (const float*)d_in[13];
    const float* W1      = (const float*)d_in[14];
    const float* b1      = (const float*)d_in[15];
    const float* W2      = (const float*)d_in[16];
    const float* b2      = (const float*)d_in[17];
    const float* ln2g    = (const float*)d_in[18];
    const float* ln2b    = (const float*)d_in[19];
    float* out = (float*)d_out;
    char*  ws  = (char*)d_ws;

    // ---- workspace layout (byte offsets) ----
    const size_t SZ_BF  = (size_t)NQ_ * 256 * 2;    // 22,282,240
    const size_t SZ_CB  = (size_t)NQ_ * 384 * 2;    // 33,423,360 (comb bf16)
    const size_t SZ_F   = (size_t)NQ_ * 256 * 4;    // 44,564,480
    ushort* s_bf    = (ushort*)(ws);                             // [0, 22.3M)
    ushort* q_bf    = (ushort*)(ws + SZ_BF);                     // [22.3M, 44.6M)
    ushort* val_bf  = (ushort*)(ws + 2 * SZ_BF);                 // [44.6M, 66.8M)
    ushort* comb    = (ushort*)(ws + 3 * SZ_BF);                 // [66.8M, 100.3M)
    ushort* samp_bf = (ushort*)(ws + 3 * SZ_BF + SZ_CB);         // [100.3M, 122.6M)
    ushort* h_bf    = (ushort*)(ws);                             // overlays [0, 89.1M): s/q/val/comb dead at FFN1
    ushort* x_bf    = (ushort*)(ws + 3 * SZ_BF + SZ_CB);         // overlays samp_bf (dead after Wout GEMM)
    char*   wbase   = ws + 3 * SZ_BF + SZ_CB + SZ_BF;            // 122.6M
    ushort* Wv_t    = (ushort*)(wbase);
    ushort* Woff_t  = (ushort*)(wbase + 131072);   // contiguous with Wattn_t -> one [384][256] Bt
    ushort* Wattn_t = (ushort*)(wbase + 262144);
    ushort* Wout_t  = (ushort*)(wbase + 327680);
    ushort* W1_t    = (ushort*)(wbase + 458752);
    ushort* W2_t    = (ushort*)(wbase + 983040);
    char*   fbase   = wbase + 1507328;                           // 124.1M
    float*  xf      = (float*)(fbase);                           // fp32 LN1 out (LN2 residual)
    ushort* src2b   = (ushort*)(fbase + SZ_F);                   // bf16 Wout out; later ffn2b
    ushort* ffn2b   = src2b;                                     // overlay (src2b dead after LN1)

    // 0. fused prep: bf16 inputs + all weight transposes (one launch)
    prep<<<dim3(TPREP_ + (NQ_ * 256 / 4) / 256), 256, 0, stream>>>(
        src, pos, s_bf, q_bf, W_value, W_off, W_attn, W_out, W1, W2,
        Wv_t, Woff_t, Wattn_t, Wout_t, W1_t, W2_t);

    const int MT = NQ_ / BM;  // 340

    // 1. fused: value = src @ Wv + bv (bf16), comb = q @ [Woff|Wattn] (bf16)
    gemm_vc<<<dim3(5 * MT), 256, 0, stream>>>(s_bf, q_bf, Wv_t, Woff_t, b_value, val_bf, comb);
    // 2. fused softmax + sampling -> bf16
    msda_sample<<<dim3(NQ_ / 2), 256, 0, stream>>>(val_bf, comb, b_off, b_attn, refp, samp_bf);
    // 3. src2 = sampled @ Wout + bout -> bf16 (consumed only by LN1)
    mfma_gemm<<<dim3(2, MT), 256, 0, stream>>>(samp_bf, Wout_t, b_out, nullptr, src2b, 256, 256, 0);
    // 4. x = LN(src + src2) -> fp32 xf + bf16 x_bf
    add_ln<<<dim3(NQ_ / 4), 256, 0, stream>>>(src, src2b, ln1g, ln1b, xf, x_bf);
    // 5. h = relu(x @ W1 + b1) -> bf16
    mfma_gemm<<<dim3(8, MT), 256, 0, stream>>>(x_bf, W1_t, b1, nullptr, h_bf, 1024, 256, 1);
    // 6. ffn2 = h @ W2 + b2 -> bf16 (consumed only by LN2)
    mfma_gemm<<<dim3(2, MT), 256, 0, stream>>>(h_bf, W2_t, b2, nullptr, ffn2b, 256, 1024, 0);
    // 7. out = LN(x + ffn2)
    add_ln<<<dim3(NQ_ / 4), 256, 0, stream>>>(xf, ffn2b, ln2g, ln2b, out, nullptr);
}

// Round 10
// 418.995 us; speedup vs baseline: 1.1101x; 1.0322x over previous
//
#include <hip/hip_runtime.h>
#include <math.h>

#define LQ_ 5440
#define NB_ 8
#define NQ_ (NB_ * LQ_)   // 43520
#define D_  256
#define NH_ 8
#define HD_ 32

typedef __attribute__((ext_vector_type(8))) short short8;
typedef __attribute__((ext_vector_type(4))) float f32x4;

__device__ __forceinline__ ushort f2bf(float f) {
    union { float f; unsigned u; } v; v.f = f;
    unsigned u = v.u;
    unsigned r = (u + 0x7FFFu + ((u >> 16) & 1u)) >> 16;
    return (ushort)r;
}
__device__ __forceinline__ float bf2f(ushort u) {
    union { unsigned u; float f; } v; v.u = ((unsigned)u) << 16; return v.f;
}

// async global->LDS, 16 B per lane. LDS dest = wave-uniform base + lane*16.
__device__ __forceinline__ void gload_lds16(const void* g, void* l) {
    __builtin_amdgcn_global_load_lds(
        (const __attribute__((address_space(1))) void*)g,
        (__attribute__((address_space(3))) void*)l, 16, 0, 0);
}

// raw workgroup barrier, fenced so no memory op is scheduled across it.
__device__ __forceinline__ void wg_barrier() {
    __builtin_amdgcn_sched_barrier(0);
    __builtin_amdgcn_s_barrier();
    __builtin_amdgcn_sched_barrier(0);
}

// bijective XCD-chunk swizzle.
__device__ __forceinline__ int xcd_swz(int flat, int nwg) {
    const int xc  = flat & 7;
    const int sl  = flat >> 3;
    const int q8  = nwg >> 3;
    const int rm8 = nwg & 7;
    return (xc < rm8 ? xc * (q8 + 1) : rm8 * (q8 + 1) + (xc - rm8) * q8) + sl;
}

// ---------------------------------------------------------------------------
// Fused prep: ONE launch for bf16 input casts + all 6 weight transposes.
// ---------------------------------------------------------------------------
#define TPREP_ 736

__global__ __launch_bounds__(256)
void prep(const float* __restrict__ src, const float* __restrict__ pos,
          ushort* __restrict__ s_bf, ushort* __restrict__ q_bf,
          const float* __restrict__ Wv, const float* __restrict__ Woff,
          const float* __restrict__ Wattn, const float* __restrict__ Wout,
          const float* __restrict__ W1, const float* __restrict__ W2,
          ushort* __restrict__ Wv_t, ushort* __restrict__ Woff_t,
          ushort* __restrict__ Wattn_t, ushort* __restrict__ Wout_t,
          ushort* __restrict__ W1_t, ushort* __restrict__ W2_t) {
    __shared__ float tile[32][33];
    const int bid = blockIdx.x;
    const int tid = threadIdx.x;

    if (bid >= TPREP_) {
        const int i = (bid - TPREP_) * 256 + tid;
        const float4 s = ((const float4*)src)[i];
        const float4 p = ((const float4*)pos)[i];
        ushort4 a, b;
        a.x = f2bf(s.x); a.y = f2bf(s.y); a.z = f2bf(s.z); a.w = f2bf(s.w);
        b.x = f2bf(s.x + p.x); b.y = f2bf(s.y + p.y);
        b.z = f2bf(s.z + p.z); b.w = f2bf(s.w + p.w);
        ((ushort4*)s_bf)[i] = a;
        ((ushort4*)q_bf)[i] = b;
        return;
    }

    const float* W; ushort* Wt; int K, N, bx, by;
    if (bid < 64)       { W = Wv;    Wt = Wv_t;    K = 256;  N = 256;  bx = bid % 8;         by = bid / 8; }
    else if (bid < 128) { W = Woff;  Wt = Woff_t;  K = 256;  N = 256;  bx = (bid-64) % 8;    by = (bid-64) / 8; }
    else if (bid < 160) { W = Wattn; Wt = Wattn_t; K = 256;  N = 128;  bx = (bid-128) % 4;   by = (bid-128) / 4; }
    else if (bid < 224) { W = Wout;  Wt = Wout_t;  K = 256;  N = 256;  bx = (bid-160) % 8;   by = (bid-160) / 8; }
    else if (bid < 480) { W = W1;    Wt = W1_t;    K = 256;  N = 1024; bx = (bid-224) % 32;  by = (bid-224) / 32; }
    else                { W = W2;    Wt = W2_t;    K = 1024; N = 256;  bx = (bid-480) % 8;   by = (bid-480) / 8; }

    const int tx = tid & 31;
    const int ty = tid >> 5;
    for (int i = ty; i < 32; i += 8)
        tile[i][tx] = W[(size_t)(by * 32 + i) * N + bx * 32 + tx];
    __syncthreads();
    for (int i = ty; i < 32; i += 8)
        Wt[(size_t)(bx * 32 + i) * K + by * 32 + tx] = f2bf(tile[tx][i]);
}

// ---------------------------------------------------------------------------
// Shared MFMA GEMM body (128x128 tile, BK=64, 4 waves, 4x4 16x16x32/wave).
// Double-buffered, counted vmcnt (waits only the PREVIOUS tile's 8 loads).
// ---------------------------------------------------------------------------
#define BM 128
#define BN 128
#define BK 64

__device__ __forceinline__ void gemm_body(
    ushort* __restrict__ lAb, ushort* __restrict__ lBb,
    const ushort* __restrict__ A, const ushort* __restrict__ Bt,
    const float* __restrict__ bias, float* __restrict__ Cf,
    ushort* __restrict__ Cb, int N, int K, int relu, int col0, int row0) {
    const int t    = threadIdx.x;
    const int w    = t >> 6;
    const int lr   = t & 15;
    const int quad = (t >> 4) & 3;
    const int wm   = (w >> 1) * 64;
    const int wn   = (w & 1) * 64;

    f32x4 acc[4][4];
    #pragma unroll
    for (int i = 0; i < 4; ++i)
        #pragma unroll
        for (int j = 0; j < 4; ++j)
            acc[i][j] = (f32x4){0.f, 0.f, 0.f, 0.f};

    const int sr = t >> 3;
    const int sc = (t & 7) * 8;
    const size_t aoff = (size_t)(row0 + sr) * K + sc;
    const size_t boff = (size_t)(col0 + sr) * K + sc;
    const int wb = w * 1024;

    auto stage = [&](int buf, int k0) {
        char* la = (char*)(lAb + buf * (BM * BK)) + wb;
        char* lb = (char*)(lBb + buf * (BN * BK)) + wb;
        #pragma unroll
        for (int g = 0; g < 4; ++g) {
            gload_lds16(A  + aoff + k0 + (size_t)g * 32 * K, la + g * 4096);
            gload_lds16(Bt + boff + k0 + (size_t)g * 32 * K, lb + g * 4096);
        }
    };

    stage(0, 0);
    int cur = 0;
    for (int k0 = 0; k0 < K; k0 += BK) {
        if (k0 + BK < K) {
            stage(cur ^ 1, k0 + BK);
            asm volatile("s_waitcnt vmcnt(8)" ::: "memory");
        } else {
            asm volatile("s_waitcnt vmcnt(0)" ::: "memory");
        }
        wg_barrier();
        const ushort* pA = lAb + cur * (BM * BK);
        const ushort* pB = lBb + cur * (BN * BK);
        #pragma unroll
        for (int kk = 0; kk < 2; ++kk) {
            short8 af[4], bfr[4];
            #pragma unroll
            for (int i = 0; i < 4; ++i)
                af[i] = *(const short8*)(pA + (wm + i * 16 + lr) * BK + kk * 32 + quad * 8);
            #pragma unroll
            for (int j = 0; j < 4; ++j)
                bfr[j] = *(const short8*)(pB + (wn + j * 16 + lr) * BK + kk * 32 + quad * 8);
            #pragma unroll
            for (int i = 0; i < 4; ++i)
                #pragma unroll
                for (int j = 0; j < 4; ++j)
                    acc[i][j] = __builtin_amdgcn_mfma_f32_16x16x32_bf16(af[i], bfr[j], acc[i][j], 0, 0, 0);
        }
        wg_barrier();
        cur ^= 1;
    }

    #pragma unroll
    for (int j = 0; j < 4; ++j) {
        const int col = col0 + wn + j * 16 + lr;
        const float bb = bias ? bias[col] : 0.f;
        #pragma unroll
        for (int i = 0; i < 4; ++i) {
            const int rbase = row0 + wm + i * 16 + quad * 4;
            #pragma unroll
            for (int r = 0; r < 4; ++r) {
                float v = acc[i][j][r] + bb;
                if (relu) v = fmaxf(v, 0.f);
                if (Cf) Cf[(size_t)(rbase + r) * N + col] = v;
                else    Cb[(size_t)(rbase + r) * N + col] = f2bf(v);
            }
        }
    }
}

// generic GEMM: grid (N/BN, M/BM), XCD-chunked bijective mapping.
__global__ __launch_bounds__(256)
void mfma_gemm(const ushort* __restrict__ A, const ushort* __restrict__ Bt,
               const float* __restrict__ bias, float* __restrict__ Cf,
               ushort* __restrict__ Cb, int N, int K, int relu) {
    __shared__ ushort lA[2][BM * BK];
    __shared__ ushort lB[2][BN * BK];
    const int nt  = gridDim.x;
    const int wi  = xcd_swz(blockIdx.y * nt + blockIdx.x, nt * gridDim.y);
    gemm_body(&lA[0][0], &lB[0][0], A, Bt, bias, Cf, Cb, N, K, relu,
              (wi % nt) * BN, (wi / nt) * BM);
}

// fused value+comb GEMM: grid 1700 = 340 row panels x (2 value + 3 comb cols).
__global__ __launch_bounds__(256)
void gemm_vc(const ushort* __restrict__ s_bf, const ushort* __restrict__ q_bf,
             const ushort* __restrict__ Wv_t, const ushort* __restrict__ Woff_t,
             const float* __restrict__ b_value,
             ushort* __restrict__ val_bf, ushort* __restrict__ comb_bf) {
    __shared__ ushort lA[2][BM * BK];
    __shared__ ushort lB[2][BN * BK];
    const int wi   = xcd_swz(blockIdx.x, gridDim.x);
    const int ci   = wi % 5;
    const int row0 = (wi / 5) * BM;
    if (ci < 2)
        gemm_body(&lA[0][0], &lB[0][0], s_bf, Wv_t, b_value, nullptr, val_bf,
                  256, 256, 0, ci * BN, row0);
    else
        gemm_body(&lA[0][0], &lB[0][0], q_bf, Woff_t, nullptr, nullptr, comb_bf,
                  384, 256, 0, (ci - 2) * BN, row0);
}

// ---------------------------------------------------------------------------
// Fused softmax + deformable bilinear sampling.  (proven r4/r6/r9 structure:
// 2 queries/block, 128 threads/query, scalar FMA, XCD swizzle, bf16 comb.)
// r10: offset/fw division replaced by exact pow2 reciprocal (exp bit-trick).
// ---------------------------------------------------------------------------
__global__ __launch_bounds__(256)
void msda_sample(const ushort* __restrict__ value, const ushort* __restrict__ comb,
                 const float* __restrict__ b_off, const float* __restrict__ b_attn,
                 const float* __restrict__ refp, ushort* __restrict__ out) {
    __shared__ int   s_addr[256][4];
    __shared__ float s_w[256][4];

    const int t   = threadIdx.x;
    const int tq  = t >> 7;
    const int u   = t & 127;
    const int bid = blockIdx.x;
    const int swz = (bid & 7) * (NQ_ / 2 / 8) + (bid >> 3);
    const int nq  = swz * 2 + tq;
    const int n   = nq / LQ_;

    // ---------------- phase 1: (h,p) ----------------
    {
        const int h = u >> 4;
        const int p = u & 15;
        const int l = p >> 2;

        const int starts[4] = {0, 4096, 5120, 5376};
        const int Wl = 64 >> l;

        float a = bf2f(comb[(size_t)nq * 384 + 256 + u]) + b_attn[u];
        float m = a;
        #pragma unroll
        for (int o = 8; o > 0; o >>= 1) m = fmaxf(m, __shfl_xor(m, o));
        float e = __expf(a - m);
        float s = e;
        #pragma unroll
        for (int o = 8; o > 0; o >>= 1) s += __shfl_xor(s, o);
        const float wgt = e / s;

        const float rx = refp[(size_t)nq * 8 + l * 2 + 0];
        const float ry = refp[(size_t)nq * 8 + l * 2 + 1];
        const uint  opk = *(const uint*)(comb + (size_t)nq * 384 + u * 2);
        const float ox = bf2f((ushort)(opk & 0xffffu)) + b_off[u * 2 + 0];
        const float oy = bf2f((ushort)(opk >> 16))     + b_off[u * 2 + 1];

        // fw = 2^(6-l); rinv = 2^-(6-l) exactly, via exponent bits (no div).
        union { uint ui; float f; } fwu, rvu;
        fwu.ui = (uint)(133 - l) << 23;   // 2^(6-l)
        rvu.ui = (uint)(121 + l) << 23;   // 2^-(6-l)
        const float fw = fwu.f;
        const float x  = (rx + ox * rvu.f) * fw - 0.5f;
        const float y  = (ry + oy * rvu.f) * fw - 0.5f;
        const float x0f = floorf(x), y0f = floorf(y);
        const int   x0 = (int)x0f, y0 = (int)y0f;
        const float wx1 = x - x0f, wy1 = y - y0f;
        const float wx0 = 1.f - wx1, wy0 = 1.f - wy1;

        const float xm0 = (x0 >= 0 && x0 < Wl) ? 1.f : 0.f;
        const float xm1 = (x0 + 1 >= 0 && x0 + 1 < Wl) ? 1.f : 0.f;
        const float ym0 = (y0 >= 0 && y0 < Wl) ? 1.f : 0.f;
        const float ym1 = (y0 + 1 >= 0 && y0 + 1 < Wl) ? 1.f : 0.f;

        const int x0c = min(max(x0, 0), Wl - 1);
        const int x1c = min(max(x0 + 1, 0), Wl - 1);
        const int y0c = min(max(y0, 0), Wl - 1);
        const int y1c = min(max(y0 + 1, 0), Wl - 1);

        const int base = (n * LQ_ + starts[l]) * 512 + h * 64;
        s_addr[t][0] = base + (y0c * Wl + x0c) * 512;
        s_addr[t][1] = base + (y0c * Wl + x1c) * 512;
        s_addr[t][2] = base + (y1c * Wl + x0c) * 512;
        s_addr[t][3] = base + (y1c * Wl + x1c) * 512;
        s_w[t][0] = wgt * wy0 * wx0 * ym0 * xm0;
        s_w[t][1] = wgt * wy0 * wx1 * ym0 * xm1;
        s_w[t][2] = wgt * wy1 * wx0 * ym1 * xm0;
        s_w[t][3] = wgt * wy1 * wx1 * ym1 * xm1;
    }
    __syncthreads();

    // ---------------- phase 2: (h,d2) ----------------
    {
        const int h   = u >> 4;
        const int d2  = u & 15;
        const int sb  = tq * 128 + h * 16;
        const uint dby = (uint)(d2 * 4);
        const char* vbase = (const char*)value;

        float acc0 = 0.f, acc1 = 0.f;
        #pragma unroll 8
        for (int p = 0; p < 16; ++p) {
            const int*   ap = s_addr[sb + p];
            const float* wp = s_w[sb + p];
            #pragma unroll
            for (int c = 0; c < 4; ++c) {
                const uint v = *(const uint*)(vbase + ((uint)ap[c] + dby));
                const float w = wp[c];
                union { uint u; float f; } lo, hi;
                lo.u = v << 16;
                hi.u = v & 0xffff0000u;
                acc0 = fmaf(lo.f, w, acc0);
                acc1 = fmaf(hi.f, w, acc1);
            }
        }
        const uint packed = (uint)f2bf(acc0) | ((uint)f2bf(acc1) << 16);
        ((uint*)out)[(size_t)nq * 128 + u] = packed;
    }
}

// ---------------------------------------------------------------------------
// y = LayerNorm(a + b). a: fp32 (af) OR bf16 (ab); b: bf16 GEMM output.
// Outputs: optional fp32 outf, optional bf16 outb.
// Wave-per-row, 4 elems/lane, shuffle-only reduce. grid = NQ/4.
// ---------------------------------------------------------------------------
__global__ __launch_bounds__(256)
void add_ln(const float* __restrict__ af, const ushort* __restrict__ ab,
            const ushort* __restrict__ b,
            const float* __restrict__ g, const float* __restrict__ be,
            float* __restrict__ outf, ushort* __restrict__ outb) {
    const int row  = blockIdx.x * 4 + (threadIdx.x >> 6);
    const int lane = threadIdx.x & 63;
    const size_t base = (size_t)row * 256 + lane * 4;

    float4 av;
    if (af) {
        av = *(const float4*)(af + base);
    } else {
        const ushort4 a4 = *(const ushort4*)(ab + base);
        av.x = bf2f(a4.x); av.y = bf2f(a4.y); av.z = bf2f(a4.z); av.w = bf2f(a4.w);
    }
    const ushort4 bv = *(const ushort4*)(b + base);
    float4 x;
    x.x = av.x + bf2f(bv.x); x.y = av.y + bf2f(bv.y);
    x.z = av.z + bf2f(bv.z); x.w = av.w + bf2f(bv.w);

    float s = x.x + x.y + x.z + x.w;
    #pragma unroll
    for (int o = 32; o > 0; o >>= 1) s += __shfl_xor(s, o);
    const float mu = s * (1.f / 256.f);

    float4 dx;
    dx.x = x.x - mu; dx.y = x.y - mu; dx.z = x.z - mu; dx.w = x.w - mu;
    float vv = dx.x * dx.x + dx.y * dx.y + dx.z * dx.z + dx.w * dx.w;
    #pragma unroll
    for (int o = 32; o > 0; o >>= 1) vv += __shfl_xor(vv, o);
    const float rstd = rsqrtf(vv * (1.f / 256.f) + 1e-5f);

    const float4 gv  = *(const float4*)(g  + lane * 4);
    const float4 bev = *(const float4*)(be + lane * 4);
    float4 y;
    y.x = dx.x * rstd * gv.x + bev.x;
    y.y = dx.y * rstd * gv.y + bev.y;
    y.z = dx.z * rstd * gv.z + bev.z;
    y.w = dx.w * rstd * gv.w + bev.w;

    if (outf) *(float4*)(outf + base) = y;
    if (outb) {
        ushort4 yb;
        yb.x = f2bf(y.x); yb.y = f2bf(y.y); yb.z = f2bf(y.z); yb.w = f2bf(y.w);
        *(ushort4*)(outb + base) = yb;
    }
}

// ---------------------------------------------------------------------------
extern "C" void kernel_launch(void* const* d_in, const int* in_sizes, int n_in,
                              void* d_out, int out_size, void* d_ws, size_t ws_size,
                              hipStream_t stream) {
    const float* src     = (const float*)d_in[0];
    const float* pos     = (const float*)d_in[1];
    const float* refp    = (const float*)d_in[2];
    const float* W_value = (const float*)d_in[4];
    const float* b_value = (const float*)d_in[5];
    const float* W_off   = (const float*)d_in[6];
    const float* b_off   = (const float*)d_in[7];
    const float* W_attn  = (const float*)d_in[8];
    const float* b_attn  = (const float*)d_in[9];
    const float* W_out   = (const float*)d_in[10];
    const float* b_out   = (const float*)d_in[11];
    const float* ln1g    = (const float*)d_in[12];
    const float* ln1b    = (const float*)d_in[13];
    const float* W1      = (const float*)d_in[14];
    const float* b1      = (const float*)d_in[15];
    const float* W2      = (const float*)d_in[16];
    const float* b2      = (const float*)d_in[17];
    const float* ln2g    = (const float*)d_in[18];
    const float* ln2b    = (const float*)d_in[19];
    float* out = (float*)d_out;
    char*  ws  = (char*)d_ws;

    // ---- workspace layout (byte offsets) ----
    const size_t SZ_BF  = (size_t)NQ_ * 256 * 2;    // 22,282,240
    const size_t SZ_CB  = (size_t)NQ_ * 384 * 2;    // 33,423,360 (comb bf16)
    ushort* s_bf    = (ushort*)(ws);                             // [0, 22.3M)
    ushort* q_bf    = (ushort*)(ws + SZ_BF);                     // [22.3M, 44.6M)
    ushort* val_bf  = (ushort*)(ws + 2 * SZ_BF);                 // [44.6M, 66.8M)
    ushort* comb    = (ushort*)(ws + 3 * SZ_BF);                 // [66.8M, 100.3M)
    ushort* samp_bf = (ushort*)(ws + 3 * SZ_BF + SZ_CB);         // [100.3M, 122.6M)
    ushort* h_bf    = (ushort*)(ws);                             // overlays [0, 89.1M): s/q/val/comb dead at FFN1
    ushort* x_bf    = (ushort*)(ws + 3 * SZ_BF + SZ_CB);         // overlays samp_bf (dead after Wout GEMM)
    char*   wbase   = ws + 3 * SZ_BF + SZ_CB + SZ_BF;            // 122.6M
    ushort* Wv_t    = (ushort*)(wbase);
    ushort* Woff_t  = (ushort*)(wbase + 131072);   // contiguous with Wattn_t -> one [384][256] Bt
    ushort* Wattn_t = (ushort*)(wbase + 262144);
    ushort* Wout_t  = (ushort*)(wbase + 327680);
    ushort* W1_t    = (ushort*)(wbase + 458752);
    ushort* W2_t    = (ushort*)(wbase + 983040);
    char*   fbase   = wbase + 1507328;                           // 124.1M
    ushort* src2b   = (ushort*)(fbase);                          // bf16 Wout out
    ushort* ffn2b   = src2b;                                     // overlay (src2b dead after LN1)

    // 0. fused prep: bf16 inputs + all weight transposes (one launch)
    prep<<<dim3(TPREP_ + (NQ_ * 256 / 4) / 256), 256, 0, stream>>>(
        src, pos, s_bf, q_bf, W_value, W_off, W_attn, W_out, W1, W2,
        Wv_t, Woff_t, Wattn_t, Wout_t, W1_t, W2_t);

    const int MT = NQ_ / BM;  // 340

    // 1. fused: value = src @ Wv + bv (bf16), comb = q @ [Woff|Wattn] (bf16)
    gemm_vc<<<dim3(5 * MT), 256, 0, stream>>>(s_bf, q_bf, Wv_t, Woff_t, b_value, val_bf, comb);
    // 2. fused softmax + sampling -> bf16
    msda_sample<<<dim3(NQ_ / 2), 256, 0, stream>>>(val_bf, comb, b_off, b_attn, refp, samp_bf);
    // 3. src2 = sampled @ Wout + bout -> bf16 (consumed only by LN1)
    mfma_gemm<<<dim3(2, MT), 256, 0, stream>>>(samp_bf, Wout_t, b_out, nullptr, src2b, 256, 256, 0);
    // 4. x = LN(src + src2) -> bf16 x_bf only (fp32 copy eliminated)
    add_ln<<<dim3(NQ_ / 4), 256, 0, stream>>>(src, nullptr, src2b, ln1g, ln1b, nullptr, x_bf);
    // 5. h = relu(x @ W1 + b1) -> bf16
    mfma_gemm<<<dim3(8, MT), 256, 0, stream>>>(x_bf, W1_t, b1, nullptr, h_bf, 1024, 256, 1);
    // 6. ffn2 = h @ W2 + b2 -> bf16 (consumed only by LN2)
    mfma_gemm<<<dim3(2, MT), 256, 0, stream>>>(h_bf, W2_t, b2, nullptr, ffn2b, 256, 1024, 0);
    // 7. out = LN(x + ffn2), residual from bf16 x_bf
    add_ln<<<dim3(NQ_ / 4), 256, 0, stream>>>(nullptr, x_bf, ffn2b, ln2g, ln2b, out, nullptr);
}

// Round 11
// 418.284 us; speedup vs baseline: 1.1120x; 1.0017x over previous
//
#include <hip/hip_runtime.h>
#include <math.h>

#define LQ_ 5440
#define NB_ 8
#define NQ_ (NB_ * LQ_)   // 43520
#define D_  256
#define NH_ 8
#define HD_ 32

typedef __attribute__((ext_vector_type(8))) short short8;
typedef __attribute__((ext_vector_type(4))) float f32x4;

__device__ __forceinline__ ushort f2bf(float f) {
    union { float f; unsigned u; } v; v.f = f;
    unsigned u = v.u;
    unsigned r = (u + 0x7FFFu + ((u >> 16) & 1u)) >> 16;
    return (ushort)r;
}
__device__ __forceinline__ float bf2f(ushort u) {
    union { unsigned u; float f; } v; v.u = ((unsigned)u) << 16; return v.f;
}

// async global->LDS, 16 B per lane. LDS dest = wave-uniform base + lane*16.
__device__ __forceinline__ void gload_lds16(const void* g, void* l) {
    __builtin_amdgcn_global_load_lds(
        (const __attribute__((address_space(1))) void*)g,
        (__attribute__((address_space(3))) void*)l, 16, 0, 0);
}

// raw workgroup barrier, fenced so no memory op is scheduled across it.
__device__ __forceinline__ void wg_barrier() {
    __builtin_amdgcn_sched_barrier(0);
    __builtin_amdgcn_s_barrier();
    __builtin_amdgcn_sched_barrier(0);
}

// bijective XCD-chunk swizzle.
__device__ __forceinline__ int xcd_swz(int flat, int nwg) {
    const int xc  = flat & 7;
    const int sl  = flat >> 3;
    const int q8  = nwg >> 3;
    const int rm8 = nwg & 7;
    return (xc < rm8 ? xc * (q8 + 1) : rm8 * (q8 + 1) + (xc - rm8) * q8) + sl;
}

// ---------------------------------------------------------------------------
// Fused prep: ONE launch for bf16 input casts + all 6 weight transposes.
// ---------------------------------------------------------------------------
#define TPREP_ 736

__global__ __launch_bounds__(256)
void prep(const float* __restrict__ src, const float* __restrict__ pos,
          ushort* __restrict__ s_bf, ushort* __restrict__ q_bf,
          const float* __restrict__ Wv, const float* __restrict__ Woff,
          const float* __restrict__ Wattn, const float* __restrict__ Wout,
          const float* __restrict__ W1, const float* __restrict__ W2,
          ushort* __restrict__ Wv_t, ushort* __restrict__ Woff_t,
          ushort* __restrict__ Wattn_t, ushort* __restrict__ Wout_t,
          ushort* __restrict__ W1_t, ushort* __restrict__ W2_t) {
    __shared__ float tile[32][33];
    const int bid = blockIdx.x;
    const int tid = threadIdx.x;

    if (bid >= TPREP_) {
        const int i = (bid - TPREP_) * 256 + tid;
        const float4 s = ((const float4*)src)[i];
        const float4 p = ((const float4*)pos)[i];
        ushort4 a, b;
        a.x = f2bf(s.x); a.y = f2bf(s.y); a.z = f2bf(s.z); a.w = f2bf(s.w);
        b.x = f2bf(s.x + p.x); b.y = f2bf(s.y + p.y);
        b.z = f2bf(s.z + p.z); b.w = f2bf(s.w + p.w);
        ((ushort4*)s_bf)[i] = a;
        ((ushort4*)q_bf)[i] = b;
        return;
    }

    const float* W; ushort* Wt; int K, N, bx, by;
    if (bid < 64)       { W = Wv;    Wt = Wv_t;    K = 256;  N = 256;  bx = bid % 8;         by = bid / 8; }
    else if (bid < 128) { W = Woff;  Wt = Woff_t;  K = 256;  N = 256;  bx = (bid-64) % 8;    by = (bid-64) / 8; }
    else if (bid < 160) { W = Wattn; Wt = Wattn_t; K = 256;  N = 128;  bx = (bid-128) % 4;   by = (bid-128) / 4; }
    else if (bid < 224) { W = Wout;  Wt = Wout_t;  K = 256;  N = 256;  bx = (bid-160) % 8;   by = (bid-160) / 8; }
    else if (bid < 480) { W = W1;    Wt = W1_t;    K = 256;  N = 1024; bx = (bid-224) % 32;  by = (bid-224) / 32; }
    else                { W = W2;    Wt = W2_t;    K = 1024; N = 256;  bx = (bid-480) % 8;   by = (bid-480) / 8; }

    const int tx = tid & 31;
    const int ty = tid >> 5;
    for (int i = ty; i < 32; i += 8)
        tile[i][tx] = W[(size_t)(by * 32 + i) * N + bx * 32 + tx];
    __syncthreads();
    for (int i = ty; i < 32; i += 8)
        Wt[(size_t)(bx * 32 + i) * K + by * 32 + tx] = f2bf(tile[tx][i]);
}

// ---------------------------------------------------------------------------
// Shared MFMA GEMM body (128x128 tile, BK=64, 4 waves, 4x4 16x16x32/wave).
// Double-buffered, counted vmcnt (waits only the PREVIOUS tile's 8 loads).
// ---------------------------------------------------------------------------
#define BM 128
#define BN 128
#define BK 64

__device__ __forceinline__ void gemm_body(
    ushort* __restrict__ lAb, ushort* __restrict__ lBb,
    const ushort* __restrict__ A, const ushort* __restrict__ Bt,
    const float* __restrict__ bias, float* __restrict__ Cf,
    ushort* __restrict__ Cb, int N, int K, int relu, int col0, int row0) {
    const int t    = threadIdx.x;
    const int w    = t >> 6;
    const int lr   = t & 15;
    const int quad = (t >> 4) & 3;
    const int wm   = (w >> 1) * 64;
    const int wn   = (w & 1) * 64;

    f32x4 acc[4][4];
    #pragma unroll
    for (int i = 0; i < 4; ++i)
        #pragma unroll
        for (int j = 0; j < 4; ++j)
            acc[i][j] = (f32x4){0.f, 0.f, 0.f, 0.f};

    const int sr = t >> 3;
    const int sc = (t & 7) * 8;
    const size_t aoff = (size_t)(row0 + sr) * K + sc;
    const size_t boff = (size_t)(col0 + sr) * K + sc;
    const int wb = w * 1024;

    auto stage = [&](int buf, int k0) {
        char* la = (char*)(lAb + buf * (BM * BK)) + wb;
        char* lb = (char*)(lBb + buf * (BN * BK)) + wb;
        #pragma unroll
        for (int g = 0; g < 4; ++g) {
            gload_lds16(A  + aoff + k0 + (size_t)g * 32 * K, la + g * 4096);
            gload_lds16(Bt + boff + k0 + (size_t)g * 32 * K, lb + g * 4096);
        }
    };

    stage(0, 0);
    int cur = 0;
    for (int k0 = 0; k0 < K; k0 += BK) {
        if (k0 + BK < K) {
            stage(cur ^ 1, k0 + BK);
            asm volatile("s_waitcnt vmcnt(8)" ::: "memory");
        } else {
            asm volatile("s_waitcnt vmcnt(0)" ::: "memory");
        }
        wg_barrier();
        const ushort* pA = lAb + cur * (BM * BK);
        const ushort* pB = lBb + cur * (BN * BK);
        #pragma unroll
        for (int kk = 0; kk < 2; ++kk) {
            short8 af[4], bfr[4];
            #pragma unroll
            for (int i = 0; i < 4; ++i)
                af[i] = *(const short8*)(pA + (wm + i * 16 + lr) * BK + kk * 32 + quad * 8);
            #pragma unroll
            for (int j = 0; j < 4; ++j)
                bfr[j] = *(const short8*)(pB + (wn + j * 16 + lr) * BK + kk * 32 + quad * 8);
            #pragma unroll
            for (int i = 0; i < 4; ++i)
                #pragma unroll
                for (int j = 0; j < 4; ++j)
                    acc[i][j] = __builtin_amdgcn_mfma_f32_16x16x32_bf16(af[i], bfr[j], acc[i][j], 0, 0, 0);
        }
        wg_barrier();
        cur ^= 1;
    }

    #pragma unroll
    for (int j = 0; j < 4; ++j) {
        const int col = col0 + wn + j * 16 + lr;
        const float bb = bias ? bias[col] : 0.f;
        #pragma unroll
        for (int i = 0; i < 4; ++i) {
            const int rbase = row0 + wm + i * 16 + quad * 4;
            #pragma unroll
            for (int r = 0; r < 4; ++r) {
                float v = acc[i][j][r] + bb;
                if (relu) v = fmaxf(v, 0.f);
                if (Cf) Cf[(size_t)(rbase + r) * N + col] = v;
                else    Cb[(size_t)(rbase + r) * N + col] = f2bf(v);
            }
        }
    }
}

// generic GEMM: grid (N/BN, M/BM), XCD-chunked bijective mapping.
__global__ __launch_bounds__(256)
void mfma_gemm(const ushort* __restrict__ A, const ushort* __restrict__ Bt,
               const float* __restrict__ bias, float* __restrict__ Cf,
               ushort* __restrict__ Cb, int N, int K, int relu) {
    __shared__ ushort lA[2][BM * BK];
    __shared__ ushort lB[2][BN * BK];
    const int nt  = gridDim.x;
    const int wi  = xcd_swz(blockIdx.y * nt + blockIdx.x, nt * gridDim.y);
    gemm_body(&lA[0][0], &lB[0][0], A, Bt, bias, Cf, Cb, N, K, relu,
              (wi % nt) * BN, (wi / nt) * BM);
}

// fused value+comb GEMM: grid 1700 = 340 row panels x (2 value + 3 comb cols).
__global__ __launch_bounds__(256)
void gemm_vc(const ushort* __restrict__ s_bf, const ushort* __restrict__ q_bf,
             const ushort* __restrict__ Wv_t, const ushort* __restrict__ Woff_t,
             const float* __restrict__ b_value,
             ushort* __restrict__ val_bf, ushort* __restrict__ comb_bf) {
    __shared__ ushort lA[2][BM * BK];
    __shared__ ushort lB[2][BN * BK];
    const int wi   = xcd_swz(blockIdx.x, gridDim.x);
    const int ci   = wi % 5;
    const int row0 = (wi / 5) * BM;
    if (ci < 2)
        gemm_body(&lA[0][0], &lB[0][0], s_bf, Wv_t, b_value, nullptr, val_bf,
                  256, 256, 0, ci * BN, row0);
    else
        gemm_body(&lA[0][0], &lB[0][0], q_bf, Woff_t, nullptr, nullptr, comb_bf,
                  384, 256, 0, (ci - 2) * BN, row0);
}

// ---------------------------------------------------------------------------
// Fused softmax + deformable bilinear sampling.  (proven structure:
// 2 queries/block, 128 threads/query, scalar FMA, XCD swizzle, bf16 comb,
// pow2 reciprocal.)  r11: softmax without max-subtraction (logits O(10),
// shift-invariant) + rcp multiply; phase-2 p-loop fully unrolled.
// ---------------------------------------------------------------------------
__global__ __launch_bounds__(256)
void msda_sample(const ushort* __restrict__ value, const ushort* __restrict__ comb,
                 const float* __restrict__ b_off, const float* __restrict__ b_attn,
                 const float* __restrict__ refp, ushort* __restrict__ out) {
    __shared__ int   s_addr[256][4];
    __shared__ float s_w[256][4];

    const int t   = threadIdx.x;
    const int tq  = t >> 7;
    const int u   = t & 127;
    const int bid = blockIdx.x;
    const int swz = (bid & 7) * (NQ_ / 2 / 8) + (bid >> 3);
    const int nq  = swz * 2 + tq;
    const int n   = nq / LQ_;

    // ---------------- phase 1: (h,p) ----------------
    {
        const int h = u >> 4;
        const int p = u & 15;
        const int l = p >> 2;

        const int starts[4] = {0, 4096, 5120, 5376};
        const int Wl = 64 >> l;

        // softmax over 16 points; no max-sub (shift-invariant, |a| small).
        const float a = bf2f(comb[(size_t)nq * 384 + 256 + u]) + b_attn[u];
        const float e = __expf(a);
        float s = e;
        #pragma unroll
        for (int o = 8; o > 0; o >>= 1) s += __shfl_xor(s, o);
        const float wgt = e * __builtin_amdgcn_rcpf(s);

        const float rx = refp[(size_t)nq * 8 + l * 2 + 0];
        const float ry = refp[(size_t)nq * 8 + l * 2 + 1];
        const uint  opk = *(const uint*)(comb + (size_t)nq * 384 + u * 2);
        const float ox = bf2f((ushort)(opk & 0xffffu)) + b_off[u * 2 + 0];
        const float oy = bf2f((ushort)(opk >> 16))     + b_off[u * 2 + 1];

        // fw = 2^(6-l); rinv = 2^-(6-l) exactly, via exponent bits (no div).
        union { uint ui; float f; } fwu, rvu;
        fwu.ui = (uint)(133 - l) << 23;   // 2^(6-l)
        rvu.ui = (uint)(121 + l) << 23;   // 2^-(6-l)
        const float fw = fwu.f;
        const float x  = (rx + ox * rvu.f) * fw - 0.5f;
        const float y  = (ry + oy * rvu.f) * fw - 0.5f;
        const float x0f = floorf(x), y0f = floorf(y);
        const int   x0 = (int)x0f, y0 = (int)y0f;
        const float wx1 = x - x0f, wy1 = y - y0f;
        const float wx0 = 1.f - wx1, wy0 = 1.f - wy1;

        const float xm0 = (x0 >= 0 && x0 < Wl) ? 1.f : 0.f;
        const float xm1 = (x0 + 1 >= 0 && x0 + 1 < Wl) ? 1.f : 0.f;
        const float ym0 = (y0 >= 0 && y0 < Wl) ? 1.f : 0.f;
        const float ym1 = (y0 + 1 >= 0 && y0 + 1 < Wl) ? 1.f : 0.f;

        const int x0c = min(max(x0, 0), Wl - 1);
        const int x1c = min(max(x0 + 1, 0), Wl - 1);
        const int y0c = min(max(y0, 0), Wl - 1);
        const int y1c = min(max(y0 + 1, 0), Wl - 1);

        const int base = (n * LQ_ + starts[l]) * 512 + h * 64;
        s_addr[t][0] = base + (y0c * Wl + x0c) * 512;
        s_addr[t][1] = base + (y0c * Wl + x1c) * 512;
        s_addr[t][2] = base + (y1c * Wl + x0c) * 512;
        s_addr[t][3] = base + (y1c * Wl + x1c) * 512;
        s_w[t][0] = wgt * wy0 * wx0 * ym0 * xm0;
        s_w[t][1] = wgt * wy0 * wx1 * ym0 * xm1;
        s_w[t][2] = wgt * wy1 * wx0 * ym1 * xm0;
        s_w[t][3] = wgt * wy1 * wx1 * ym1 * xm1;
    }
    __syncthreads();

    // ---------------- phase 2: (h,d2) ----------------
    {
        const int h   = u >> 4;
        const int d2  = u & 15;
        const int sb  = tq * 128 + h * 16;
        const uint dby = (uint)(d2 * 4);
        const char* vbase = (const char*)value;

        float acc0 = 0.f, acc1 = 0.f;
        #pragma unroll
        for (int p = 0; p < 16; ++p) {
            const int*   ap = s_addr[sb + p];
            const float* wp = s_w[sb + p];
            #pragma unroll
            for (int c = 0; c < 4; ++c) {
                const uint v = *(const uint*)(vbase + ((uint)ap[c] + dby));
                const float w = wp[c];
                union { uint u; float f; } lo, hi;
                lo.u = v << 16;
                hi.u = v & 0xffff0000u;
                acc0 = fmaf(lo.f, w, acc0);
                acc1 = fmaf(hi.f, w, acc1);
            }
        }
        const uint packed = (uint)f2bf(acc0) | ((uint)f2bf(acc1) << 16);
        ((uint*)out)[(size_t)nq * 128 + u] = packed;
    }
}

// ---------------------------------------------------------------------------
// y = LayerNorm(a + b). a: fp32 (af) OR bf16 (ab); b: bf16 GEMM output.
// Outputs: optional fp32 outf, optional bf16 outb.
// Wave-per-row, 4 elems/lane, shuffle-only reduce. grid = NQ/4.
// ---------------------------------------------------------------------------
__global__ __launch_bounds__(256)
void add_ln(const float* __restrict__ af, const ushort* __restrict__ ab,
            const ushort* __restrict__ b,
            const float* __restrict__ g, const float* __restrict__ be,
            float* __restrict__ outf, ushort* __restrict__ outb) {
    const int row  = blockIdx.x * 4 + (threadIdx.x >> 6);
    const int lane = threadIdx.x & 63;
    const size_t base = (size_t)row * 256 + lane * 4;

    float4 av;
    if (af) {
        av = *(const float4*)(af + base);
    } else {
        const ushort4 a4 = *(const ushort4*)(ab + base);
        av.x = bf2f(a4.x); av.y = bf2f(a4.y); av.z = bf2f(a4.z); av.w = bf2f(a4.w);
    }
    const ushort4 bv = *(const ushort4*)(b + base);
    float4 x;
    x.x = av.x + bf2f(bv.x); x.y = av.y + bf2f(bv.y);
    x.z = av.z + bf2f(bv.z); x.w = av.w + bf2f(bv.w);

    float s = x.x + x.y + x.z + x.w;
    #pragma unroll
    for (int o = 32; o > 0; o >>= 1) s += __shfl_xor(s, o);
    const float mu = s * (1.f / 256.f);

    float4 dx;
    dx.x = x.x - mu; dx.y = x.y - mu; dx.z = x.z - mu; dx.w = x.w - mu;
    float vv = dx.x * dx.x + dx.y * dx.y + dx.z * dx.z + dx.w * dx.w;
    #pragma unroll
    for (int o = 32; o > 0; o >>= 1) vv += __shfl_xor(vv, o);
    const float rstd = rsqrtf(vv * (1.f / 256.f) + 1e-5f);

    const float4 gv  = *(const float4*)(g  + lane * 4);
    const float4 bev = *(const float4*)(be + lane * 4);
    float4 y;
    y.x = dx.x * rstd * gv.x + bev.x;
    y.y = dx.y * rstd * gv.y + bev.y;
    y.z = dx.z * rstd * gv.z + bev.z;
    y.w = dx.w * rstd * gv.w + bev.w;

    if (outf) *(float4*)(outf + base) = y;
    if (outb) {
        ushort4 yb;
        yb.x = f2bf(y.x); yb.y = f2bf(y.y); yb.z = f2bf(y.z); yb.w = f2bf(y.w);
        *(ushort4*)(outb + base) = yb;
    }
}

// ---------------------------------------------------------------------------
extern "C" void kernel_launch(void* const* d_in, const int* in_sizes, int n_in,
                              void* d_out, int out_size, void* d_ws, size_t ws_size,
                              hipStream_t stream) {
    const float* src     = (const float*)d_in[0];
    const float* pos     = (const float*)d_in[1];
    const float* refp    = (const float*)d_in[2];
    const float* W_value = (const float*)d_in[4];
    const float* b_value = (const float*)d_in[5];
    const float* W_off   = (const float*)d_in[6];
    const float* b_off   = (const float*)d_in[7];
    const float* W_attn  = (const float*)d_in[8];
    const float* b_attn  = (const float*)d_in[9];
    const float* W_out   = (const float*)d_in[10];
    const float* b_out   = (const float*)d_in[11];
    const float* ln1g    = (const float*)d_in[12];
    const float* ln1b    = (const float*)d_in[13];
    const float* W1      = (const float*)d_in[14];
    const float* b1      = (const float*)d_in[15];
    const float* W2      = (const float*)d_in[16];
    const float* b2      = (const float*)d_in[17];
    const float* ln2g    = (const float*)d_in[18];
    const float* ln2b    = (const float*)d_in[19];
    float* out = (float*)d_out;
    char*  ws  = (char*)d_ws;

    // ---- workspace layout (byte offsets) ----
    const size_t SZ_BF  = (size_t)NQ_ * 256 * 2;    // 22,282,240
    const size_t SZ_CB  = (size_t)NQ_ * 384 * 2;    // 33,423,360 (comb bf16)
    ushort* s_bf    = (ushort*)(ws);                             // [0, 22.3M)
    ushort* q_bf    = (ushort*)(ws + SZ_BF);                     // [22.3M, 44.6M)
    ushort* val_bf  = (ushort*)(ws + 2 * SZ_BF);                 // [44.6M, 66.8M)
    ushort* comb    = (ushort*)(ws + 3 * SZ_BF);                 // [66.8M, 100.3M)
    ushort* samp_bf = (ushort*)(ws + 3 * SZ_BF + SZ_CB);         // [100.3M, 122.6M)
    ushort* h_bf    = (ushort*)(ws);                             // overlays [0, 89.1M): s/q/val/comb dead at FFN1
    ushort* x_bf    = (ushort*)(ws + 3 * SZ_BF + SZ_CB);         // overlays samp_bf (dead after Wout GEMM)
    char*   wbase   = ws + 3 * SZ_BF + SZ_CB + SZ_BF;            // 122.6M
    ushort* Wv_t    = (ushort*)(wbase);
    ushort* Woff_t  = (ushort*)(wbase + 131072);   // contiguous with Wattn_t -> one [384][256] Bt
    ushort* Wattn_t = (ushort*)(wbase + 262144);
    ushort* Wout_t  = (ushort*)(wbase + 327680);
    ushort* W1_t    = (ushort*)(wbase + 458752);
    ushort* W2_t    = (ushort*)(wbase + 983040);
    char*   fbase   = wbase + 1507328;                           // 124.1M
    ushort* src2b   = (ushort*)(fbase);                          // bf16 Wout out
    ushort* ffn2b   = src2b;                                     // overlay (src2b dead after LN1)

    // 0. fused prep: bf16 inputs + all weight transposes (one launch)
    prep<<<dim3(TPREP_ + (NQ_ * 256 / 4) / 256), 256, 0, stream>>>(
        src, pos, s_bf, q_bf, W_value, W_off, W_attn, W_out, W1, W2,
        Wv_t, Woff_t, Wattn_t, Wout_t, W1_t, W2_t);

    const int MT = NQ_ / BM;  // 340

    // 1. fused: value = src @ Wv + bv (bf16), comb = q @ [Woff|Wattn] (bf16)
    gemm_vc<<<dim3(5 * MT), 256, 0, stream>>>(s_bf, q_bf, Wv_t, Woff_t, b_value, val_bf, comb);
    // 2. fused softmax + sampling -> bf16
    msda_sample<<<dim3(NQ_ / 2), 256, 0, stream>>>(val_bf, comb, b_off, b_attn, refp, samp_bf);
    // 3. src2 = sampled @ Wout + bout -> bf16 (consumed only by LN1)
    mfma_gemm<<<dim3(2, MT), 256, 0, stream>>>(samp_bf, Wout_t, b_out, nullptr, src2b, 256, 256, 0);
    // 4. x = LN(s_bf + src2) -> bf16 x_bf (residual from bf16 src cast; s_bf
    //    still alive — h_bf overlay is only written at step 5)
    add_ln<<<dim3(NQ_ / 4), 256, 0, stream>>>(nullptr, s_bf, src2b, ln1g, ln1b, nullptr, x_bf);
    // 5. h = relu(x @ W1 + b1) -> bf16
    mfma_gemm<<<dim3(8, MT), 256, 0, stream>>>(x_bf, W1_t, b1, nullptr, h_bf, 1024, 256, 1);
    // 6. ffn2 = h @ W2 + b2 -> bf16 (consumed only by LN2)
    mfma_gemm<<<dim3(2, MT), 256, 0, stream>>>(h_bf, W2_t, b2, nullptr, ffn2b, 256, 1024, 0);
    // 7. out = LN(x + ffn2), residual from bf16 x_bf
    add_ln<<<dim3(NQ_ / 4), 256, 0, stream>>>(nullptr, x_bf, ffn2b, ln2g, ln2b, out, nullptr);
}